// Round 11
// baseline (365.293 us; speedup 1.0000x reference)
//
#include <hip/hip_runtime.h>
#include <hip/hip_bf16.h>
#include <math.h>

typedef __hip_bfloat16 bf16;
typedef __attribute__((ext_vector_type(8))) short short8;
typedef __attribute__((ext_vector_type(4))) float floatx4;
typedef __attribute__((ext_vector_type(4))) unsigned int uint4v;
typedef __attribute__((ext_vector_type(2))) unsigned int uint2v;

#define HW 16384          // 128*128
#define NSLICE 243        // 9*9*3

// ---- band tables (anti-diagonals of 9x9 grid) ----
__constant__ int c_s_of_p[81] = {
  0, 1,1, 2,2,2, 3,3,3,3, 4,4,4,4,4, 5,5,5,5,5,5, 6,6,6,6,6,6,6,
  7,7,7,7,7,7,7,7, 8,8,8,8,8,8,8,8,8, 9,9,9,9,9,9,9,9,
  10,10,10,10,10,10,10, 11,11,11,11,11,11, 12,12,12,12,12,
  13,13,13,13, 14,14,14, 15,15, 16};
__constant__ int c_l_of_p[81] = {
  0, 0,1, 0,1,2, 0,1,2,3, 0,1,2,3,4, 0,1,2,3,4,5, 0,1,2,3,4,5,6,
  0,1,2,3,4,5,6,7, 0,1,2,3,4,5,6,7,8, 0,1,2,3,4,5,6,7,
  0,1,2,3,4,5,6, 0,1,2,3,4,5, 0,1,2,3,4, 0,1,2,3, 0,1,2, 0,1, 0};
__constant__ int c_L_of_s[17] = {1,2,3,4,5,6,7,8,9,8,7,6,5,4,3,2,1};
__constant__ int c_g_of_s[17] = {0,1,1,2,2,2,2,2,2,3,3,3,3,3,3,3,3};
__constant__ int c_pos_uv[81] = {
  0,1,3,6,10,15,21,28,36,
  2,4,7,11,16,22,29,37,45,
  5,8,12,17,23,30,38,46,53,
  9,13,18,24,31,39,47,54,60,
  14,19,25,32,40,48,55,61,66,
  20,26,33,41,49,56,62,67,71,
  27,34,42,50,57,63,68,72,75,
  35,43,51,58,64,69,73,76,78,
  44,52,59,65,70,74,77,79,80};

struct WPtrs {
  const float* wi[4]; const float* bi[4]; const float* a[4];
  const float* wb[4]; const float* bb[4]; const float* wl;
};

__device__ __forceinline__ unsigned short f2bf(float f) {
  return __bfloat16_as_ushort(__float2bfloat16(f));
}
__device__ __forceinline__ float bf2f(unsigned short u) {
  return __uint_as_float(((unsigned int)u) << 16);
}
__device__ __forceinline__ float bflo(unsigned int w) {
  return __uint_as_float(w << 16);
}
__device__ __forceinline__ float bfhi(unsigned int w) {
  return __uint_as_float(w & 0xffff0000u);
}
__device__ __forceinline__ unsigned int pack2(float a, float b) {
  return (unsigned int)f2bf(a) | ((unsigned int)f2bf(b) << 16);
}
// inverse PReLU: raw = v>=0 ? v : v*invA  (exact for alpha = power of two)
__device__ __forceinline__ float invprelu(float v, float invA) {
  return (v >= 0.f) ? v : v * invA;
}
// split fp32 into bf16 hi (truncate) + bf16 lo (RNE of remainder): ~2^-17 rel
__device__ __forceinline__ void bfsplit(float v, unsigned short& hi, unsigned short& lo) {
  unsigned int bits = __float_as_uint(v);
  hi = (unsigned short)(bits >> 16);
  lo = f2bf(v - __uint_as_float(bits & 0xffff0000u));
}
// async global->LDS 16B: LDS dest = wave-uniform base + lane*16
__device__ __forceinline__ void gl_lds16(const void* g, void* l) {
  __builtin_amdgcn_global_load_lds(
      (const __attribute__((address_space(1))) unsigned int*)g,
      (__attribute__((address_space(3))) unsigned int*)l, 16, 0, 0);
}
// conv LDS plane layout with bank-phase swizzle: plane stride 2112 B, plus
// (plane&3)*32 B so consecutive planes land on phases {0,96,64,32} mod 128 B.
__device__ __forceinline__ int ldsoff(int plane, int col) {
  return plane * 2112 + ((plane & 3) << 5) + (col << 4);
}
// Da entry via exact integer mod-36 angle reduction (f32, <=2ulp):
// Da[U][u] = cos(pi*U*(2u+1)/18)*sqrt(2/9); U==0 -> 1/3 exactly.
__device__ __forceinline__ float da_entry(int t) {
  int U = t / 9, u = t % 9;
  if (U == 0) return 0.33333334f;
  int m9 = (U * (2 * u + 1)) % 36;
  return cosf((float)m9 * 0.17453293f) * 0.47140452f;   // pi/18
}
// Wmf repack body (dct2-fwd side blocks)
__device__ __forceinline__ void wmf_repack(const WPtrs& P, unsigned short* Wmf, int t) {
  if (t >= 92160) return;
  int s = t / 7680, r = t % 7680;
  int step = r / 512, r2 = r % 512;
  int lane = r2 >> 3, j = r2 & 7;
  int d = step / 5, i = step % 5;
  int q = lane >> 4, m = lane & 15;
  int tl = 2 * i + (q >> 1);
  int cin = (q & 1) * 8 + j;
  float val = 0.f;
  if (tl <= 8) {
    int ky = tl / 3, kx = tl % 3;
    int tap = d * 9 + ky * 3 + kx;
    if (s < 4) {
      if (cin < 3) val = P.wi[s][(m * 3 + cin) * 27 + tap];
    } else {
      int g = (s - 4) >> 1, k = (s - 4) & 1;
      val = P.wb[g][((k * 16 + m) * 16 + cin) * 27 + tap];
    }
  }
  Wmf[t] = f2bf(val);
}

// ---- fused spatial DCT: Y = Dop * X * Dop^T per 128x128 slice ----
// Self-contained: DCT table computed in-kernel into LDS (int mod-512 angle
// reduction + cosf). Fwd launch carries 90 side blocks for Wmf repack.
__global__ __launch_bounds__(1024) void k_dct2(const float* __restrict__ X,
                                               const float* __restrict__ xres,
                                               float* __restrict__ Yf,
                                               unsigned short* __restrict__ Ybf,
                                               WPtrs P,
                                               unsigned short* __restrict__ Wmf) {
  if (blockIdx.x >= 243) {              // side blocks: weight repack
    int t2 = (blockIdx.x - 243) * 1024 + threadIdx.x;
    wmf_repack(P, Wmf, t2);
    return;
  }
  extern __shared__ char dynlds[];
  unsigned short* sThi = (unsigned short*)dynlds;              // 34816 B
  unsigned short* sTlo = (unsigned short*)(dynlds + 34816);    // 34816 B
  unsigned short* sBhi = (unsigned short*)(dynlds + 69632);    // 32768 B
  unsigned short* sBlo = (unsigned short*)(dynlds + 102400);   // 32768 B
  int s = blockIdx.x;
  int t = threadIdx.x;
  int lane = t & 63, wv16 = t >> 6;     // 0..15
  int mt8 = wv16 & 7, nh = wv16 >> 3;   // row-group 0..7, nt-half 0..1
  int q = lane >> 4, n16 = lane & 15;
  const float* Xs = X + (size_t)s * HW;
  int isFwd = (Ybf != nullptr);

  // ---- in-LDS DCT table (layout identical to the old global table) ----
  for (int i = t; i < 16384; i += 1024) {
    int jj = i & 7, ln = (i >> 3) & 63, ks = (i >> 9) & 3, tile = i >> 11;
    int row = tile * 16 + (ln & 15);
    int colk = ks * 32 + (ln >> 4) * 8 + jj;
    int mm = isFwd ? (row * (2 * colk + 1)) & 511
                   : (colk * (2 * row + 1)) & 511;
    float vv = cosf((float)mm * 0.012271846f) * 0.125f;   // pi/256; sqrt(2/128)=1/8
    if (isFwd ? (row == 0) : (colk == 0)) vv *= 0.70710678f;
    unsigned short hh, ll;
    bfsplit(vv, hh, ll);
    sBhi[i] = hh; sBlo[i] = ll;
  }
  __syncthreads();

  floatx4 acc[4];
#pragma unroll
  for (int ntl = 0; ntl < 4; ntl++) acc[ntl] = (floatx4){0.f, 0.f, 0.f, 0.f};

#pragma unroll
  for (int ks = 0; ks < 4; ks++) {
    short8 ahi, alo;
    {
      const float* xp = Xs + (mt8 * 16 + n16) * 128 + ks * 32 + q * 8;
      float4 a = *(const float4*)xp;
      float4 b = *(const float4*)(xp + 4);
      union { short8 v; unsigned short u[8]; } H, L;
      float xv[8] = {a.x, a.y, a.z, a.w, b.x, b.y, b.z, b.w};
#pragma unroll
      for (int j = 0; j < 8; j++) bfsplit(xv[j], H.u[j], L.u[j]);
      ahi = H.v; alo = L.v;
    }
#pragma unroll
    for (int ntl = 0; ntl < 4; ntl++) {
      int e = (nh * 4 + ntl) * 2048 + ks * 512 + lane * 8;
      short8 bh = *(const short8*)(sBhi + e);
      short8 bl = *(const short8*)(sBlo + e);
      acc[ntl] = __builtin_amdgcn_mfma_f32_16x16x32_bf16(ahi, bl, acc[ntl], 0, 0, 0);
      acc[ntl] = __builtin_amdgcn_mfma_f32_16x16x32_bf16(alo, bh, acc[ntl], 0, 0, 0);
      acc[ntl] = __builtin_amdgcn_mfma_f32_16x16x32_bf16(ahi, bh, acc[ntl], 0, 0, 0);
    }
  }

#pragma unroll
  for (int ntl = 0; ntl < 4; ntl++) {
    int col = (nh * 4 + ntl) * 16 + n16;
    int rowb = mt8 * 16 + q * 4;
#pragma unroll
    for (int rp = 0; rp < 4; rp += 2) {
      unsigned short h0, l0, h1, l1;
      bfsplit(acc[ntl][rp], h0, l0);
      bfsplit(acc[ntl][rp + 1], h1, l1);
      int widx = (col * 136 + rowb + rp) >> 1;
      ((unsigned int*)sThi)[widx] = (unsigned int)h0 | ((unsigned int)h1 << 16);
      ((unsigned int*)sTlo)[widx] = (unsigned int)l0 | ((unsigned int)l1 << 16);
    }
  }
  __syncthreads();

#pragma unroll
  for (int ntl = 0; ntl < 4; ntl++) acc[ntl] = (floatx4){0.f, 0.f, 0.f, 0.f};

#pragma unroll
  for (int ks = 0; ks < 4; ks++) {
    int e0 = mt8 * 2048 + ks * 512 + lane * 8;
    short8 ahi = *(const short8*)(sBhi + e0);
    short8 alo = *(const short8*)(sBlo + e0);
#pragma unroll
    for (int ntl = 0; ntl < 4; ntl++) {
      int off = ((nh * 4 + ntl) * 16 + n16) * 136 + ks * 32 + q * 8;
      short8 bh = *(const short8*)(sThi + off);
      short8 bl = *(const short8*)(sTlo + off);
      acc[ntl] = __builtin_amdgcn_mfma_f32_16x16x32_bf16(ahi, bl, acc[ntl], 0, 0, 0);
      acc[ntl] = __builtin_amdgcn_mfma_f32_16x16x32_bf16(alo, bh, acc[ntl], 0, 0, 0);
      acc[ntl] = __builtin_amdgcn_mfma_f32_16x16x32_bf16(ahi, bh, acc[ntl], 0, 0, 0);
    }
  }

#pragma unroll
  for (int ntl = 0; ntl < 4; ntl++) {
    int row0 = mt8 * 16 + q * 4;
    int col = (nh * 4 + ntl) * 16 + n16;
#pragma unroll
    for (int r = 0; r < 4; r++) {
      size_t oi = (size_t)s * HW + (size_t)(row0 + r) * 128 + col;
      float v = acc[ntl][r];
      if (Ybf) {
        Ybf[oi] = f2bf(v);
      } else {
        if (xres) v += xres[oi];
        Yf[oi] = v;
      }
    }
  }
}

// ---- fused forward angular DCT: out[U][V] = Da F Da^T per (c,hw) point ----
__global__ __launch_bounds__(256) void k_angfwd(const unsigned short* __restrict__ in,
                                                unsigned short* __restrict__ out) {
  __shared__ float sDa[81];
  int t = threadIdx.x;
  if (t < 81) sDa[t] = da_entry(t);
  __syncthreads();
  int idx = blockIdx.x * 256 + t;       // 9*HW total
  int hw = idx & (HW - 1);
  int r = idx >> 14;                    // 0..8
  int c = r % 3, ub = r / 3;            // ub: which 3 U rows
  unsigned short raw[81];
#pragma unroll
  for (int u = 0; u < 9; u++)
#pragma unroll
    for (int v = 0; v < 9; v++)
      raw[u * 9 + v] = in[(size_t)((u * 9 + v) * 3 + c) * HW + hw];
  float tmp[3][9];
#pragma unroll
  for (int i = 0; i < 3; i++)
#pragma unroll
    for (int v = 0; v < 9; v++) tmp[i][v] = 0.f;
#pragma unroll
  for (int u = 0; u < 9; u++) {
    float fv[9];
#pragma unroll
    for (int v = 0; v < 9; v++) fv[v] = bf2f(raw[u * 9 + v]);
#pragma unroll
    for (int i = 0; i < 3; i++) {
      float dc = sDa[(ub * 3 + i) * 9 + u];
#pragma unroll
      for (int v = 0; v < 9; v++) tmp[i][v] += dc * fv[v];
    }
  }
#pragma unroll
  for (int i = 0; i < 3; i++) {
    int U = ub * 3 + i;
#pragma unroll
    for (int V = 0; V < 9; V++) {
      float acc = 0.f;
#pragma unroll
      for (int v = 0; v < 9; v++) acc += sDa[V * 9 + v] * tmp[i][v];
      out[(size_t)(c_pos_uv[U * 9 + V] * 3 + c) * HW + hw] = f2bf(acc);
    }
  }
}

// ---- fused inverse angular DCT: out[u][v] = Da^T F Da per (c,hw) point ----
__global__ __launch_bounds__(256) void k_anginv(const float* __restrict__ xrb,
                                                float* __restrict__ out) {
  __shared__ float sDa[81];
  int t = threadIdx.x;
  if (t < 81) sDa[t] = da_entry(t);
  __syncthreads();
  int idx = blockIdx.x * 256 + t;       // 9*HW total
  int hw = idx & (HW - 1);
  int r = idx >> 14;
  int c = r % 3, ub = r / 3;            // ub: which 3 u rows
  float raw[81];
#pragma unroll
  for (int U = 0; U < 9; U++)
#pragma unroll
    for (int V = 0; V < 9; V++)
      raw[U * 9 + V] = xrb[((size_t)c_pos_uv[U * 9 + V] * 3 + c) * HW + hw];
  float tmp[3][9];
#pragma unroll
  for (int i = 0; i < 3; i++)
#pragma unroll
    for (int V = 0; V < 9; V++) tmp[i][V] = 0.f;
#pragma unroll
  for (int U = 0; U < 9; U++) {
#pragma unroll
    for (int i = 0; i < 3; i++) {
      float dc = sDa[U * 9 + (ub * 3 + i)];
#pragma unroll
      for (int V = 0; V < 9; V++) tmp[i][V] += dc * raw[U * 9 + V];
    }
  }
#pragma unroll
  for (int i = 0; i < 3; i++) {
    int u = ub * 3 + i;
#pragma unroll
    for (int v = 0; v < 9; v++) {
      float acc = 0.f;
#pragma unroll
      for (int V = 0; V < 9; V++) acc += sDa[V * 9 + v] * tmp[i][V];
      out[(size_t)((u * 9 + v) * 3 + c) * HW + hw] = acc;
    }
  }
}

// ---- MFMA implicit-GEMM 3x3x3 conv, 8 output rows per 1024-thread block ----
// v6: DOUBLE-BUFFERED LDS slabs. Slab k+1's global_load_lds DMA is issued
// BEFORE slab k's compute; the vmcnt(0) drain happens after compute, so
// HBM latency hides under MFMA. Raw s_barrier + explicit waitcnt between
// phases (NOT __syncthreads, which would drain vmcnt before compute).
// Race audit: stage(buf) issues only after the barrier that ends all reads
// of buf; each slab's vmcnt(0)+barrier precedes its compute. Epilogue reads
// the center plane (always the last slab, d=1) from the final buffer.
// 84.7 KB LDS -> 1 block/CU (occupancy proven non-binding in r3).
__global__ __launch_bounds__(1024, 4) void k_conv(const unsigned short* __restrict__ src,
                                              const unsigned short* __restrict__ act0,
                                              const unsigned short* __restrict__ Wmf,
                                              WPtrs P,
                                              int sel,
                                              unsigned short* __restrict__ boutAct,
                                              float* __restrict__ xrbOut) {
  __shared__ unsigned short s_lds[2][21184];   // 2 x 42368 B (swizzled planes)
  int p = blockIdx.y;
  int s = c_s_of_p[p], l = c_l_of_p[p];
  int g = c_g_of_s[s], Ls = c_L_of_s[s];
  int row0 = blockIdx.x * 8;
  int t = threadIdx.x;
  int lane = t & 63, wv16 = t >> 6;     // wv16 0..15
  int row8 = wv16 & 7, ch = wv16 >> 3;  // wave: row row8, col-half ch
  int q = lane >> 4, n = lane & 15;

  float aNext = (sel < 2) ? P.a[g][sel] : 0.f;
  float invA  = (sel > 0) ? 1.0f / P.a[g][sel - 1] : 0.f;

  // ---- static zero region (BOTH buffers): halo cols 0/129; sel0 half==1
  // plane; OOB rows ----
#pragma unroll
  for (int bb = 0; bb < 2; bb++) {
    char* lb = (char*)s_lds[bb];
    uint4v z = (uint4v){0u, 0u, 0u, 0u};
    int zmax = (sel == 0) ? 1320 : 40;
    for (int i = t; i < zmax; i += 1024) {
      int row, half, col;
      if (i < 40) { row = i >> 2; half = (i >> 1) & 1; col = (i & 1) ? 129 : 0; }
      else { int j = i - 40; row = j >> 7; col = (j & 127) + 1; half = 1; }
      *(uint4v*)(lb + ldsoff(row * 2 + half, col)) = z;
    }
    for (int row = 0; row < 10; row++) {
      int grow = row0 - 1 + row;
      if ((unsigned)grow >= 128u) {
        for (int i = t; i < 264; i += 1024) {
          int half = i / 132, col = i % 132;
          *(uint4v*)(lb + ldsoff(row * 2 + half, col)) = z;
        }
      }
    }
  }

  // per-lane B-read offsets (bytes) for the 5 K-steps of a dz phase
  int off2[5];
#pragma unroll
  for (int i = 0; i < 5; i++) {
    int tl = 2 * i + (q >> 1);
    if (tl > 8) tl = 8;
    int ky = tl / 3, kx = tl % 3;
    off2[i] = ldsoff(2 * (row8 + ky) + (q & 1), n + kx) + ch * 1024;
  }

  int setIdx = (sel == 0) ? g : (4 + g * 2 + (sel - 1));
  const char* WsetBase = (const char*)Wmf + (size_t)setIdx * 15 * 1024;

  floatx4 acc[4];
#pragma unroll
  for (int cg = 0; cg < 4; cg++) acc[cg] = (floatx4){0.f, 0.f, 0.f, 0.f};

  // valid d list in order {0,2,1}: center plane (always valid) is LAST
  int dlist[3], nd = 0;
  {
    const int dord[3] = {0, 2, 1};
    for (int k = 0; k < 3; k++) {
      int d = dord[k];
      int l2 = l + d - 1;
      if (l2 >= 0 && l2 < Ls) dlist[nd++] = d;   // block-uniform
    }
  }

  auto stage = [&](int bb, int d) {     // issue staging DMA/stores for slab
    char* lb = (char*)s_lds[bb];
    int p2 = p + d - 1;
    if (sel == 0) {
#pragma unroll
      for (int it = 0; it < 2; it++) {
        int id = t + it * 1024;
        if (id < 1280) {
          int row = id >> 7, col = id & 127;
          int grow = row0 - 1 + row;      // wave-uniform
          if ((unsigned)grow < 128u) {
            const unsigned short* s0 = src + (size_t)p2 * 3 * HW +
                                       (size_t)grow * 128 + col;
            unsigned int c0 = s0[0];
            unsigned int c1 = s0[HW];
            unsigned int c2 = s0[2 * HW];
            uint4v val;
            val.x = c0 | (c1 << 16);
            val.y = c2;                   // {c2, 0}
            val.z = 0u; val.w = 0u;
            *(uint4v*)(lb + ldsoff(row * 2, col + 1)) = val;
          }
        }
      }
    } else {
#pragma unroll
      for (int it = 0; it < 3; it++) {
        int id = t + it * 1024;
        if (id < 2560) {                  // wave-uniform (2560 % 64 == 0)
          int row = id >> 8, half = (id >> 7) & 1, col = id & 127;
          int grow = row0 - 1 + row;      // wave-uniform
          if ((unsigned)grow < 128u) {
            const void* gp = (const void*)(src +
                (((size_t)p2 * HW + (size_t)grow * 128 + col) * 16 + half * 8));
            void* lp = (void*)(lb + ldsoff(row * 2 + half, col + 1));
            gl_lds16(gp, lp);
          }
        }
      }
    }
  };

  // prologue: stage first slab into buf0, full drain
  stage(0, dlist[0]);
  asm volatile("s_waitcnt vmcnt(0) lgkmcnt(0)" ::: "memory");
  __builtin_amdgcn_s_barrier();
  asm volatile("" ::: "memory");

  for (int k = 0; k < nd; k++) {
    int d = dlist[k];
    int cur = k & 1;
    // A fragments FIRST (their vmcnt-wait must not drain the prefetch below)
    short8 af[5];
#pragma unroll
    for (int i = 0; i < 5; i++)
      af[i] = *(const short8*)(WsetBase + ((d * 5 + i) * 64 + lane) * 16);
    // prefetch next slab into the other buffer (stays in flight)
    if (k + 1 < nd) stage(cur ^ 1, dlist[k + 1]);
    asm volatile("" ::: "memory");
    // compute from buf[cur]
    const char* lb = (const char*)s_lds[cur];
#pragma unroll
    for (int cg = 0; cg < 4; cg++) {
#pragma unroll
      for (int i = 0; i < 5; i++) {
        short8 b = *(const short8*)(lb + off2[i] + cg * 256);
        acc[cg] = __builtin_amdgcn_mfma_f32_16x16x32_bf16(af[i], b, acc[cg], 0, 0, 0);
      }
    }
    if (k + 1 < nd) {
      asm volatile("s_waitcnt vmcnt(0) lgkmcnt(0)" ::: "memory");
      __builtin_amdgcn_s_barrier();
      asm volatile("" ::: "memory");
    }
  }

  // ---- epilogue ----
  // Final slab = center plane p (d=1, always last), in buffer (nd-1)&1.
  const char* lbE = (const char*)s_lds[(nd - 1) & 1];
  const float* bp = (sel == 0) ? P.bi[g] : (P.bb[g] + (sel - 1) * 16);
  float bz[4];
#pragma unroll
  for (int r = 0; r < 4; r++) bz[r] = bp[q * 4 + r];
  int h = row0 + row8;

  if (sel < 2) {
#pragma unroll
    for (int cg = 0; cg < 4; cg++) {
      size_t pix = (size_t)p * HW + h * 128 + ch * 64 + cg * 16 + n;
      float r0 = acc[cg][0] + bz[0], r1 = acc[cg][1] + bz[1];
      float r2 = acc[cg][2] + bz[2], r3 = acc[cg][3] + bz[3];
      if (sel != 0) {
        uint2v pv = *(const uint2v*)(lbE +
            ldsoff(2 * (row8 + 1) + (q >> 1), ch * 64 + cg * 16 + n + 1) + (q & 1) * 8);
        r0 += invprelu(bflo(pv.x), invA); r1 += invprelu(bfhi(pv.x), invA);
        r2 += invprelu(bflo(pv.y), invA); r3 += invprelu(bfhi(pv.y), invA);
      }
      // store activated with consumer's alpha
      r0 = fmaxf(r0, 0.f) + aNext * fminf(r0, 0.f);
      r1 = fmaxf(r1, 0.f) + aNext * fminf(r1, 0.f);
      r2 = fmaxf(r2, 0.f) + aNext * fminf(r2, 0.f);
      r3 = fmaxf(r3, 0.f) + aNext * fminf(r3, 0.f);
      uint2v ov; ov.x = pack2(r0, r1); ov.y = pack2(r2, r3);
      *(uint2v*)(boutAct + pix * 16 + q * 4) = ov;
    }
  } else {
    // fused (raw0 + y2) 1x1 w_last -> xrb[p][c][hw]
    float invA0 = 1.0f / P.a[g][0];
    float wl0[4], wl1[4], wl2[4];
#pragma unroll
    for (int r = 0; r < 4; r++) {
      wl0[r] = P.wl[q * 4 + r];
      wl1[r] = P.wl[16 + q * 4 + r];
      wl2[r] = P.wl[32 + q * 4 + r];
    }
#pragma unroll
    for (int cg = 0; cg < 4; cg++) {
      size_t pix = (size_t)p * HW + h * 128 + ch * 64 + cg * 16 + n;
      float r0 = acc[cg][0] + bz[0], r1 = acc[cg][1] + bz[1];
      float r2 = acc[cg][2] + bz[2], r3 = acc[cg][3] + bz[3];
      uint2v pv = *(const uint2v*)(lbE +
          ldsoff(2 * (row8 + 1) + (q >> 1), ch * 64 + cg * 16 + n + 1) + (q & 1) * 8);
      r0 += invprelu(bflo(pv.x), invA); r1 += invprelu(bfhi(pv.x), invA);
      r2 += invprelu(bflo(pv.y), invA); r3 += invprelu(bfhi(pv.y), invA);
      uint2v p0 = *(const uint2v*)(act0 + pix * 16 + q * 4);
      r0 += invprelu(bflo(p0.x), invA0); r1 += invprelu(bfhi(p0.x), invA0);
      r2 += invprelu(bflo(p0.y), invA0); r3 += invprelu(bfhi(p0.y), invA0);
      float o0 = wl0[0] * r0 + wl0[1] * r1 + wl0[2] * r2 + wl0[3] * r3;
      float o1 = wl1[0] * r0 + wl1[1] * r1 + wl1[2] * r2 + wl1[3] * r3;
      float o2 = wl2[0] * r0 + wl2[1] * r1 + wl2[2] * r2 + wl2[3] * r3;
      o0 += __shfl_xor(o0, 16); o0 += __shfl_xor(o0, 32);
      o1 += __shfl_xor(o1, 16); o1 += __shfl_xor(o1, 32);
      o2 += __shfl_xor(o2, 16); o2 += __shfl_xor(o2, 32);
      if (q == 0) {
        size_t hw = (size_t)h * 128 + ch * 64 + cg * 16 + n;
        xrbOut[((size_t)p * 3 + 0) * HW + hw] = o0;
        xrbOut[((size_t)p * 3 + 1) * HW + hw] = o1;
        xrbOut[((size_t)p * 3 + 2) * HW + hw] = o2;
      }
    }
  }
}

extern "C" void kernel_launch(void* const* d_in, const int* in_sizes, int n_in,
                              void* d_out, int out_size, void* d_ws, size_t ws_size,
                              hipStream_t stream) {
  (void)in_sizes; (void)n_in; (void)out_size; (void)ws_size;
  const float* x = (const float*)d_in[0];
  WPtrs P;
  for (int g = 0; g < 4; g++) {
    int b = 1 + g * 5;
    P.wi[g] = (const float*)d_in[b + 0];
    P.bi[g] = (const float*)d_in[b + 1];
    P.a[g]  = (const float*)d_in[b + 2];
    P.wb[g] = (const float*)d_in[b + 3];
    P.bb[g] = (const float*)d_in[b + 4];
  }
  P.wl = (const float*)d_in[21];

  char* base = (char*)d_ws;
  size_t off = 0;
  auto take = [&](size_t bytes) -> char* {
    char* r = base + off;
    off += (bytes + 255) & ~(size_t)255;
    return r;
  };
  unsigned short* Wmf = (unsigned short*)take(92160 * 2);
  float* R1 = (float*)take((size_t)NSLICE * HW * 4);            // xr2 f32 (inv)
  unsigned short* B1 = (unsigned short*)take((size_t)NSLICE * HW * 2);  // dct2f out
  float* R3 = (float*)take((size_t)NSLICE * HW * 4);            // xf2b bf16 | xrb f32
  unsigned short* braw0 = (unsigned short*)take((size_t)81 * 16 * HW * 2);
  unsigned short* braw1 = (unsigned short*)take((size_t)81 * 16 * HW * 2);
  unsigned short* xf2b = (unsigned short*)R3;          // 8 MB < 15.9 MB
  float* xrb = R3;

  // fused forward spatial DCT (in-LDS table) + Wmf repack side blocks
  k_dct2<<<333, 1024, 135168, stream>>>(x, nullptr, nullptr, B1, P, Wmf);
  // fused forward angular DCT (preload-81 regs, in-kernel Da, plane stores)
  k_angfwd<<<576, 256, 0, stream>>>(B1, xf2b);
  // branch convs (MFMA implicit GEMM; dbuf async staging; sel2 fuses 1x1)
  k_conv<<<dim3(16, 81), 1024, 0, stream>>>(xf2b, nullptr, Wmf, P,
                                            0, braw0, nullptr);
  k_conv<<<dim3(16, 81), 1024, 0, stream>>>(braw0, nullptr, Wmf, P,
                                            1, braw1, nullptr);
  k_conv<<<dim3(16, 81), 1024, 0, stream>>>(braw1, braw0, Wmf, P,
                                            2, nullptr, xrb);
  // fused inverse angular DCT (preload-81 registers, in-kernel Da)
  k_anginv<<<576, 256, 0, stream>>>(xrb, R1);
  // fused inverse spatial DCT + residual add (in-LDS inverse table)
  k_dct2<<<243, 1024, 135168, stream>>>(R1, x, (float*)d_out, nullptr, P, Wmf);
}

// Round 12
// 263.904 us; speedup vs baseline: 1.3842x; 1.3842x over previous
//
#include <hip/hip_runtime.h>
#include <hip/hip_bf16.h>
#include <math.h>

typedef __hip_bfloat16 bf16;
typedef __attribute__((ext_vector_type(8))) short short8;
typedef __attribute__((ext_vector_type(4))) float floatx4;
typedef __attribute__((ext_vector_type(4))) unsigned int uint4v;
typedef __attribute__((ext_vector_type(2))) unsigned int uint2v;

#define HW 16384          // 128*128
#define NSLICE 243        // 9*9*3

// ---- band tables (anti-diagonals of 9x9 grid) ----
__constant__ int c_s_of_p[81] = {
  0, 1,1, 2,2,2, 3,3,3,3, 4,4,4,4,4, 5,5,5,5,5,5, 6,6,6,6,6,6,6,
  7,7,7,7,7,7,7,7, 8,8,8,8,8,8,8,8,8, 9,9,9,9,9,9,9,9,
  10,10,10,10,10,10,10, 11,11,11,11,11,11, 12,12,12,12,12,
  13,13,13,13, 14,14,14, 15,15, 16};
__constant__ int c_l_of_p[81] = {
  0, 0,1, 0,1,2, 0,1,2,3, 0,1,2,3,4, 0,1,2,3,4,5, 0,1,2,3,4,5,6,
  0,1,2,3,4,5,6,7, 0,1,2,3,4,5,6,7,8, 0,1,2,3,4,5,6,7,
  0,1,2,3,4,5,6, 0,1,2,3,4,5, 0,1,2,3,4, 0,1,2,3, 0,1,2, 0,1, 0};
__constant__ int c_L_of_s[17] = {1,2,3,4,5,6,7,8,9,8,7,6,5,4,3,2,1};
__constant__ int c_g_of_s[17] = {0,1,1,2,2,2,2,2,2,3,3,3,3,3,3,3,3};
__constant__ int c_pos_uv[81] = {
  0,1,3,6,10,15,21,28,36,
  2,4,7,11,16,22,29,37,45,
  5,8,12,17,23,30,38,46,53,
  9,13,18,24,31,39,47,54,60,
  14,19,25,32,40,48,55,61,66,
  20,26,33,41,49,56,62,67,71,
  27,34,42,50,57,63,68,72,75,
  35,43,51,58,64,69,73,76,78,
  44,52,59,65,70,74,77,79,80};

struct WPtrs {
  const float* wi[4]; const float* bi[4]; const float* a[4];
  const float* wb[4]; const float* bb[4]; const float* wl;
};

__device__ __forceinline__ unsigned short f2bf(float f) {
  return __bfloat16_as_ushort(__float2bfloat16(f));
}
__device__ __forceinline__ float bf2f(unsigned short u) {
  return __uint_as_float(((unsigned int)u) << 16);
}
__device__ __forceinline__ float bflo(unsigned int w) {
  return __uint_as_float(w << 16);
}
__device__ __forceinline__ float bfhi(unsigned int w) {
  return __uint_as_float(w & 0xffff0000u);
}
__device__ __forceinline__ unsigned int pack2(float a, float b) {
  return (unsigned int)f2bf(a) | ((unsigned int)f2bf(b) << 16);
}
// inverse PReLU: raw = v>=0 ? v : v*invA  (exact for alpha = power of two)
__device__ __forceinline__ float invprelu(float v, float invA) {
  return (v >= 0.f) ? v : v * invA;
}
// split fp32 into bf16 hi (truncate) + bf16 lo (RNE of remainder): ~2^-17 rel
__device__ __forceinline__ void bfsplit(float v, unsigned short& hi, unsigned short& lo) {
  unsigned int bits = __float_as_uint(v);
  hi = (unsigned short)(bits >> 16);
  lo = f2bf(v - __uint_as_float(bits & 0xffff0000u));
}
// async global->LDS 16B: LDS dest = wave-uniform base + lane*16
__device__ __forceinline__ void gl_lds16(const void* g, void* l) {
  __builtin_amdgcn_global_load_lds(
      (const __attribute__((address_space(1))) unsigned int*)g,
      (__attribute__((address_space(3))) unsigned int*)l, 16, 0, 0);
}
// conv LDS plane layout with bank-phase swizzle: plane stride 2112 B, plus
// (plane&3)*32 B so consecutive planes land on phases {0,96,64,32} mod 128 B.
__device__ __forceinline__ int ldsoff(int plane, int col) {
  return plane * 2112 + ((plane & 3) << 5) + (col << 4);
}
// Da entry via exact integer mod-36 angle reduction (f32, <=2ulp):
// Da[U][u] = cos(pi*U*(2u+1)/18)*sqrt(2/9); U==0 -> 1/3 exactly.
__device__ __forceinline__ float da_entry(int t) {
  int U = t / 9, u = t % 9;
  if (U == 0) return 0.33333334f;
  int m9 = (U * (2 * u + 1)) % 36;
  return cosf((float)m9 * 0.17453293f) * 0.47140452f;   // pi/18
}
// Wmf repack body (dct2-fwd side blocks)
__device__ __forceinline__ void wmf_repack(const WPtrs& P, unsigned short* Wmf, int t) {
  if (t >= 92160) return;
  int s = t / 7680, r = t % 7680;
  int step = r / 512, r2 = r % 512;
  int lane = r2 >> 3, j = r2 & 7;
  int d = step / 5, i = step % 5;
  int q = lane >> 4, m = lane & 15;
  int tl = 2 * i + (q >> 1);
  int cin = (q & 1) * 8 + j;
  float val = 0.f;
  if (tl <= 8) {
    int ky = tl / 3, kx = tl % 3;
    int tap = d * 9 + ky * 3 + kx;
    if (s < 4) {
      if (cin < 3) val = P.wi[s][(m * 3 + cin) * 27 + tap];
    } else {
      int g = (s - 4) >> 1, k = (s - 4) & 1;
      val = P.wb[g][((k * 16 + m) * 16 + cin) * 27 + tap];
    }
  }
  Wmf[t] = f2bf(val);
}

// ---- fused spatial DCT: Y = Dop * X * Dop^T per 128x128 slice ----
// Self-contained: DCT table computed in-kernel into LDS (int mod-512 angle
// reduction + cosf, <=2ulp f32 — below the bf16-split 2^-17 granularity).
// Fwd launch carries 90 side blocks (blockIdx >= 243) for the Wmf repack.
__global__ __launch_bounds__(1024) void k_dct2(const float* __restrict__ X,
                                               const float* __restrict__ xres,
                                               float* __restrict__ Yf,
                                               unsigned short* __restrict__ Ybf,
                                               WPtrs P,
                                               unsigned short* __restrict__ Wmf) {
  if (blockIdx.x >= 243) {              // side blocks: weight repack
    int t2 = (blockIdx.x - 243) * 1024 + threadIdx.x;
    wmf_repack(P, Wmf, t2);
    return;
  }
  extern __shared__ char dynlds[];
  unsigned short* sThi = (unsigned short*)dynlds;              // 34816 B
  unsigned short* sTlo = (unsigned short*)(dynlds + 34816);    // 34816 B
  unsigned short* sBhi = (unsigned short*)(dynlds + 69632);    // 32768 B
  unsigned short* sBlo = (unsigned short*)(dynlds + 102400);   // 32768 B
  int s = blockIdx.x;
  int t = threadIdx.x;
  int lane = t & 63, wv16 = t >> 6;     // 0..15
  int mt8 = wv16 & 7, nh = wv16 >> 3;   // row-group 0..7, nt-half 0..1
  int q = lane >> 4, n16 = lane & 15;
  const float* Xs = X + (size_t)s * HW;
  int isFwd = (Ybf != nullptr);

  // ---- in-LDS DCT table (layout identical to the old global table) ----
  for (int i = t; i < 16384; i += 1024) {
    int jj = i & 7, ln = (i >> 3) & 63, ks = (i >> 9) & 3, tile = i >> 11;
    int row = tile * 16 + (ln & 15);
    int colk = ks * 32 + (ln >> 4) * 8 + jj;
    int mm = isFwd ? (row * (2 * colk + 1)) & 511
                   : (colk * (2 * row + 1)) & 511;
    float vv = cosf((float)mm * 0.012271846f) * 0.125f;   // pi/256; sqrt(2/128)=1/8
    if (isFwd ? (row == 0) : (colk == 0)) vv *= 0.70710678f;
    unsigned short hh, ll;
    bfsplit(vv, hh, ll);
    sBhi[i] = hh; sBlo[i] = ll;
  }
  __syncthreads();

  floatx4 acc[4];
#pragma unroll
  for (int ntl = 0; ntl < 4; ntl++) acc[ntl] = (floatx4){0.f, 0.f, 0.f, 0.f};

#pragma unroll
  for (int ks = 0; ks < 4; ks++) {
    short8 ahi, alo;
    {
      const float* xp = Xs + (mt8 * 16 + n16) * 128 + ks * 32 + q * 8;
      float4 a = *(const float4*)xp;
      float4 b = *(const float4*)(xp + 4);
      union { short8 v; unsigned short u[8]; } H, L;
      float xv[8] = {a.x, a.y, a.z, a.w, b.x, b.y, b.z, b.w};
#pragma unroll
      for (int j = 0; j < 8; j++) bfsplit(xv[j], H.u[j], L.u[j]);
      ahi = H.v; alo = L.v;
    }
#pragma unroll
    for (int ntl = 0; ntl < 4; ntl++) {
      int e = (nh * 4 + ntl) * 2048 + ks * 512 + lane * 8;
      short8 bh = *(const short8*)(sBhi + e);
      short8 bl = *(const short8*)(sBlo + e);
      acc[ntl] = __builtin_amdgcn_mfma_f32_16x16x32_bf16(ahi, bl, acc[ntl], 0, 0, 0);
      acc[ntl] = __builtin_amdgcn_mfma_f32_16x16x32_bf16(alo, bh, acc[ntl], 0, 0, 0);
      acc[ntl] = __builtin_amdgcn_mfma_f32_16x16x32_bf16(ahi, bh, acc[ntl], 0, 0, 0);
    }
  }

#pragma unroll
  for (int ntl = 0; ntl < 4; ntl++) {
    int col = (nh * 4 + ntl) * 16 + n16;
    int rowb = mt8 * 16 + q * 4;
#pragma unroll
    for (int rp = 0; rp < 4; rp += 2) {
      unsigned short h0, l0, h1, l1;
      bfsplit(acc[ntl][rp], h0, l0);
      bfsplit(acc[ntl][rp + 1], h1, l1);
      int widx = (col * 136 + rowb + rp) >> 1;
      ((unsigned int*)sThi)[widx] = (unsigned int)h0 | ((unsigned int)h1 << 16);
      ((unsigned int*)sTlo)[widx] = (unsigned int)l0 | ((unsigned int)l1 << 16);
    }
  }
  __syncthreads();

#pragma unroll
  for (int ntl = 0; ntl < 4; ntl++) acc[ntl] = (floatx4){0.f, 0.f, 0.f, 0.f};

#pragma unroll
  for (int ks = 0; ks < 4; ks++) {
    int e0 = mt8 * 2048 + ks * 512 + lane * 8;
    short8 ahi = *(const short8*)(sBhi + e0);
    short8 alo = *(const short8*)(sBlo + e0);
#pragma unroll
    for (int ntl = 0; ntl < 4; ntl++) {
      int off = ((nh * 4 + ntl) * 16 + n16) * 136 + ks * 32 + q * 8;
      short8 bh = *(const short8*)(sThi + off);
      short8 bl = *(const short8*)(sTlo + off);
      acc[ntl] = __builtin_amdgcn_mfma_f32_16x16x32_bf16(ahi, bl, acc[ntl], 0, 0, 0);
      acc[ntl] = __builtin_amdgcn_mfma_f32_16x16x32_bf16(alo, bh, acc[ntl], 0, 0, 0);
      acc[ntl] = __builtin_amdgcn_mfma_f32_16x16x32_bf16(ahi, bh, acc[ntl], 0, 0, 0);
    }
  }

#pragma unroll
  for (int ntl = 0; ntl < 4; ntl++) {
    int row0 = mt8 * 16 + q * 4;
    int col = (nh * 4 + ntl) * 16 + n16;
#pragma unroll
    for (int r = 0; r < 4; r++) {
      size_t oi = (size_t)s * HW + (size_t)(row0 + r) * 128 + col;
      float v = acc[ntl][r];
      if (Ybf) {
        Ybf[oi] = f2bf(v);
      } else {
        if (xres) v += xres[oi];
        Yf[oi] = v;
      }
    }
  }
}

// ---- fused forward angular DCT: out[U][V] = Da F Da^T per (c,hw) point ----
__global__ __launch_bounds__(256) void k_angfwd(const unsigned short* __restrict__ in,
                                                unsigned short* __restrict__ out) {
  __shared__ float sDa[81];
  int t = threadIdx.x;
  if (t < 81) sDa[t] = da_entry(t);
  __syncthreads();
  int idx = blockIdx.x * 256 + t;       // 9*HW total
  int hw = idx & (HW - 1);
  int r = idx >> 14;                    // 0..8
  int c = r % 3, ub = r / 3;            // ub: which 3 U rows
  unsigned short raw[81];
#pragma unroll
  for (int u = 0; u < 9; u++)
#pragma unroll
    for (int v = 0; v < 9; v++)
      raw[u * 9 + v] = in[(size_t)((u * 9 + v) * 3 + c) * HW + hw];
  float tmp[3][9];
#pragma unroll
  for (int i = 0; i < 3; i++)
#pragma unroll
    for (int v = 0; v < 9; v++) tmp[i][v] = 0.f;
#pragma unroll
  for (int u = 0; u < 9; u++) {
    float fv[9];
#pragma unroll
    for (int v = 0; v < 9; v++) fv[v] = bf2f(raw[u * 9 + v]);
#pragma unroll
    for (int i = 0; i < 3; i++) {
      float dc = sDa[(ub * 3 + i) * 9 + u];
#pragma unroll
      for (int v = 0; v < 9; v++) tmp[i][v] += dc * fv[v];
    }
  }
#pragma unroll
  for (int i = 0; i < 3; i++) {
    int U = ub * 3 + i;
#pragma unroll
    for (int V = 0; V < 9; V++) {
      float acc = 0.f;
#pragma unroll
      for (int v = 0; v < 9; v++) acc += sDa[V * 9 + v] * tmp[i][v];
      out[(size_t)(c_pos_uv[U * 9 + V] * 3 + c) * HW + hw] = f2bf(acc);
    }
  }
}

// ---- fused inverse angular DCT: out[u][v] = Da^T F Da per (c,hw) point ----
__global__ __launch_bounds__(256) void k_anginv(const float* __restrict__ xrb,
                                                float* __restrict__ out) {
  __shared__ float sDa[81];
  int t = threadIdx.x;
  if (t < 81) sDa[t] = da_entry(t);
  __syncthreads();
  int idx = blockIdx.x * 256 + t;       // 9*HW total
  int hw = idx & (HW - 1);
  int r = idx >> 14;
  int c = r % 3, ub = r / 3;            // ub: which 3 u rows
  float raw[81];
#pragma unroll
  for (int U = 0; U < 9; U++)
#pragma unroll
    for (int V = 0; V < 9; V++)
      raw[U * 9 + V] = xrb[((size_t)c_pos_uv[U * 9 + V] * 3 + c) * HW + hw];
  float tmp[3][9];
#pragma unroll
  for (int i = 0; i < 3; i++)
#pragma unroll
    for (int V = 0; V < 9; V++) tmp[i][V] = 0.f;
#pragma unroll
  for (int U = 0; U < 9; U++) {
#pragma unroll
    for (int i = 0; i < 3; i++) {
      float dc = sDa[U * 9 + (ub * 3 + i)];
#pragma unroll
      for (int V = 0; V < 9; V++) tmp[i][V] += dc * raw[U * 9 + V];
    }
  }
#pragma unroll
  for (int i = 0; i < 3; i++) {
    int u = ub * 3 + i;
#pragma unroll
    for (int v = 0; v < 9; v++) {
      float acc = 0.f;
#pragma unroll
      for (int V = 0; V < 9; V++) acc += sDa[V * 9 + v] * tmp[i][V];
      out[(size_t)((u * 9 + v) * 3 + c) * HW + hw] = acc;
    }
  }
}

// ---- MFMA implicit-GEMM 3x3x3 conv, 8 output rows per 1024-thread block ----
// FINAL (structural floor ~43-47 us; 7 interventions null/regressed):
// 16 waves/block, 16x16x32 MFMA, single-buffer global_load_lds staging at
// 2 blocks/CU — cross-block overlap hides the staging drain (r11 proved
// 1-block dbuf is 1.7x worse; r3 proved more waves don't help).
// d-order {0,2,1}: center plane staged last -> epilogue reads prevAct from
// LDS. Biases/alphas/wl read directly from input tensors.
__global__ __launch_bounds__(1024, 8) void k_conv(const unsigned short* __restrict__ src,
                                              const unsigned short* __restrict__ act0,
                                              const unsigned short* __restrict__ Wmf,
                                              WPtrs P,
                                              int sel,
                                              unsigned short* __restrict__ boutAct,
                                              float* __restrict__ xrbOut) {
  __shared__ unsigned short s_lds[21184];   // 42368 B (swizzled planes)
  int p = blockIdx.y;
  int s = c_s_of_p[p], l = c_l_of_p[p];
  int g = c_g_of_s[s], Ls = c_L_of_s[s];
  int row0 = blockIdx.x * 8;
  int t = threadIdx.x;
  int lane = t & 63, wv16 = t >> 6;     // wv16 0..15
  int row8 = wv16 & 7, ch = wv16 >> 3;  // wave: row row8, col-half ch
  int q = lane >> 4, n = lane & 15;

  float aNext = (sel < 2) ? P.a[g][sel] : 0.f;
  float invA  = (sel > 0) ? 1.0f / P.a[g][sel - 1] : 0.f;

  // ---- static zero region: halo cols 0/129; sel0 half==1 plane; OOB rows ----
  {
    uint4v z = (uint4v){0u, 0u, 0u, 0u};
    int zmax = (sel == 0) ? 1320 : 40;
    for (int i = t; i < zmax; i += 1024) {
      int row, half, col;
      if (i < 40) { row = i >> 2; half = (i >> 1) & 1; col = (i & 1) ? 129 : 0; }
      else { int j = i - 40; row = j >> 7; col = (j & 127) + 1; half = 1; }
      *(uint4v*)((char*)s_lds + ldsoff(row * 2 + half, col)) = z;
    }
    // OOB rows (edge blocks only)
    for (int row = 0; row < 10; row++) {
      int grow = row0 - 1 + row;
      if ((unsigned)grow >= 128u) {
        for (int i = t; i < 264; i += 1024) {
          int half = i / 132, col = i % 132;
          *(uint4v*)((char*)s_lds + ldsoff(row * 2 + half, col)) = z;
        }
      }
    }
  }

  // per-lane B-read offsets (bytes) for the 5 K-steps of a dz phase
  int off2[5];
#pragma unroll
  for (int i = 0; i < 5; i++) {
    int tl = 2 * i + (q >> 1);
    if (tl > 8) tl = 8;
    int ky = tl / 3, kx = tl % 3;
    off2[i] = ldsoff(2 * (row8 + ky) + (q & 1), n + kx) + ch * 1024;
  }

  int setIdx = (sel == 0) ? g : (4 + g * 2 + (sel - 1));
  const char* WsetBase = (const char*)Wmf + (size_t)setIdx * 15 * 1024;

  floatx4 acc[4];
#pragma unroll
  for (int cg = 0; cg < 4; cg++) acc[cg] = (floatx4){0.f, 0.f, 0.f, 0.f};

  const int dord[3] = {0, 2, 1};        // center (always-valid) staged last
  for (int k = 0; k < 3; k++) {
    int d = dord[k];
    int l2 = l + d - 1;
    if (l2 < 0 || l2 >= Ls) continue;     // block-uniform
    int p2 = p + d - 1;
    __syncthreads();
    // ---- stage slab interior ----
    if (sel == 0) {
      // 1280 chunks (10 rows x 128 cols, half0 only); 3 plane loads + pack
#pragma unroll
      for (int it = 0; it < 2; it++) {
        int id = t + it * 1024;
        if (id < 1280) {
          int row = id >> 7, col = id & 127;
          int grow = row0 - 1 + row;      // wave-uniform
          if ((unsigned)grow < 128u) {
            const unsigned short* s0 = src + (size_t)p2 * 3 * HW +
                                       (size_t)grow * 128 + col;
            unsigned int c0 = s0[0];
            unsigned int c1 = s0[HW];
            unsigned int c2 = s0[2 * HW];
            uint4v val;
            val.x = c0 | (c1 << 16);
            val.y = c2;                   // {c2, 0}
            val.z = 0u; val.w = 0u;
            *(uint4v*)((char*)s_lds + ldsoff(row * 2, col + 1)) = val;
          }
        }
      }
    } else {
      // 2560 chunks (10 rows x 2 halves x 128 cols), async DMA
#pragma unroll
      for (int it = 0; it < 3; it++) {
        int id = t + it * 1024;
        if (id < 2560) {                  // wave-uniform (2560 % 64 == 0)
          int row = id >> 8, half = (id >> 7) & 1, col = id & 127;
          int grow = row0 - 1 + row;      // wave-uniform
          if ((unsigned)grow < 128u) {
            const void* gp = (const void*)(src +
                (((size_t)p2 * HW + (size_t)grow * 128 + col) * 16 + half * 8));
            void* lp = (void*)((char*)s_lds + ldsoff(row * 2 + half, col + 1));
            gl_lds16(gp, lp);
          }
        }
      }
    }
    __syncthreads();
    // ---- A fragments + MFMA ----
    short8 af[5];
#pragma unroll
    for (int i = 0; i < 5; i++)
      af[i] = *(const short8*)(WsetBase + ((d * 5 + i) * 64 + lane) * 16);
#pragma unroll
    for (int cg = 0; cg < 4; cg++) {
#pragma unroll
      for (int i = 0; i < 5; i++) {
        short8 b = *(const short8*)((const char*)s_lds + off2[i] + cg * 256);
        acc[cg] = __builtin_amdgcn_mfma_f32_16x16x32_bf16(af[i], b, acc[cg], 0, 0, 0);
      }
    }
  }

  // ---- epilogue ----
  // LDS holds the center plane p (rows row0-1..row0+8 as LDS rows 0..9).
  const float* bp = (sel == 0) ? P.bi[g] : (P.bb[g] + (sel - 1) * 16);
  float bz[4];
#pragma unroll
  for (int r = 0; r < 4; r++) bz[r] = bp[q * 4 + r];
  int h = row0 + row8;

  if (sel < 2) {
#pragma unroll
    for (int cg = 0; cg < 4; cg++) {
      size_t pix = (size_t)p * HW + h * 128 + ch * 64 + cg * 16 + n;
      float r0 = acc[cg][0] + bz[0], r1 = acc[cg][1] + bz[1];
      float r2 = acc[cg][2] + bz[2], r3 = acc[cg][3] + bz[3];
      if (sel != 0) {
        uint2v pv = *(const uint2v*)((const char*)s_lds +
            ldsoff(2 * (row8 + 1) + (q >> 1), ch * 64 + cg * 16 + n + 1) + (q & 1) * 8);
        r0 += invprelu(bflo(pv.x), invA); r1 += invprelu(bfhi(pv.x), invA);
        r2 += invprelu(bflo(pv.y), invA); r3 += invprelu(bfhi(pv.y), invA);
      }
      // store activated with consumer's alpha
      r0 = fmaxf(r0, 0.f) + aNext * fminf(r0, 0.f);
      r1 = fmaxf(r1, 0.f) + aNext * fminf(r1, 0.f);
      r2 = fmaxf(r2, 0.f) + aNext * fminf(r2, 0.f);
      r3 = fmaxf(r3, 0.f) + aNext * fminf(r3, 0.f);
      uint2v ov; ov.x = pack2(r0, r1); ov.y = pack2(r2, r3);
      *(uint2v*)(boutAct + pix * 16 + q * 4) = ov;
    }
  } else {
    // fused (raw0 + y2) 1x1 w_last -> xrb[p][c][hw]
    float invA0 = 1.0f / P.a[g][0];
    float wl0[4], wl1[4], wl2[4];
#pragma unroll
    for (int r = 0; r < 4; r++) {
      wl0[r] = P.wl[q * 4 + r];
      wl1[r] = P.wl[16 + q * 4 + r];
      wl2[r] = P.wl[32 + q * 4 + r];
    }
#pragma unroll
    for (int cg = 0; cg < 4; cg++) {
      size_t pix = (size_t)p * HW + h * 128 + ch * 64 + cg * 16 + n;
      float r0 = acc[cg][0] + bz[0], r1 = acc[cg][1] + bz[1];
      float r2 = acc[cg][2] + bz[2], r3 = acc[cg][3] + bz[3];
      uint2v pv = *(const uint2v*)((const char*)s_lds +
          ldsoff(2 * (row8 + 1) + (q >> 1), ch * 64 + cg * 16 + n + 1) + (q & 1) * 8);
      r0 += invprelu(bflo(pv.x), invA); r1 += invprelu(bfhi(pv.x), invA);
      r2 += invprelu(bflo(pv.y), invA); r3 += invprelu(bfhi(pv.y), invA);
      uint2v p0 = *(const uint2v*)(act0 + pix * 16 + q * 4);
      r0 += invprelu(bflo(p0.x), invA0); r1 += invprelu(bfhi(p0.x), invA0);
      r2 += invprelu(bflo(p0.y), invA0); r3 += invprelu(bfhi(p0.y), invA0);
      float o0 = wl0[0] * r0 + wl0[1] * r1 + wl0[2] * r2 + wl0[3] * r3;
      float o1 = wl1[0] * r0 + wl1[1] * r1 + wl1[2] * r2 + wl1[3] * r3;
      float o2 = wl2[0] * r0 + wl2[1] * r1 + wl2[2] * r2 + wl2[3] * r3;
      o0 += __shfl_xor(o0, 16); o0 += __shfl_xor(o0, 32);
      o1 += __shfl_xor(o1, 16); o1 += __shfl_xor(o1, 32);
      o2 += __shfl_xor(o2, 16); o2 += __shfl_xor(o2, 32);
      if (q == 0) {
        size_t hw = (size_t)h * 128 + ch * 64 + cg * 16 + n;
        xrbOut[((size_t)p * 3 + 0) * HW + hw] = o0;
        xrbOut[((size_t)p * 3 + 1) * HW + hw] = o1;
        xrbOut[((size_t)p * 3 + 2) * HW + hw] = o2;
      }
    }
  }
}

extern "C" void kernel_launch(void* const* d_in, const int* in_sizes, int n_in,
                              void* d_out, int out_size, void* d_ws, size_t ws_size,
                              hipStream_t stream) {
  (void)in_sizes; (void)n_in; (void)out_size; (void)ws_size;
  const float* x = (const float*)d_in[0];
  WPtrs P;
  for (int g = 0; g < 4; g++) {
    int b = 1 + g * 5;
    P.wi[g] = (const float*)d_in[b + 0];
    P.bi[g] = (const float*)d_in[b + 1];
    P.a[g]  = (const float*)d_in[b + 2];
    P.wb[g] = (const float*)d_in[b + 3];
    P.bb[g] = (const float*)d_in[b + 4];
  }
  P.wl = (const float*)d_in[21];

  char* base = (char*)d_ws;
  size_t off = 0;
  auto take = [&](size_t bytes) -> char* {
    char* r = base + off;
    off += (bytes + 255) & ~(size_t)255;
    return r;
  };
  unsigned short* Wmf = (unsigned short*)take(92160 * 2);
  float* R1 = (float*)take((size_t)NSLICE * HW * 4);            // xr2 f32 (inv)
  unsigned short* B1 = (unsigned short*)take((size_t)NSLICE * HW * 2);  // dct2f out
  float* R3 = (float*)take((size_t)NSLICE * HW * 4);            // xf2b bf16 | xrb f32
  unsigned short* braw0 = (unsigned short*)take((size_t)81 * 16 * HW * 2);
  unsigned short* braw1 = (unsigned short*)take((size_t)81 * 16 * HW * 2);
  unsigned short* xf2b = (unsigned short*)R3;          // 8 MB < 15.9 MB
  float* xrb = R3;

  // fused forward spatial DCT (in-LDS table) + Wmf repack side blocks
  k_dct2<<<333, 1024, 135168, stream>>>(x, nullptr, nullptr, B1, P, Wmf);
  // fused forward angular DCT (preload-81 regs, in-kernel Da, plane stores)
  k_angfwd<<<576, 256, 0, stream>>>(B1, xf2b);
  // branch convs (MFMA implicit GEMM; act-forwarding; sel2 fuses 1x1 epi)
  k_conv<<<dim3(16, 81), 1024, 0, stream>>>(xf2b, nullptr, Wmf, P,
                                            0, braw0, nullptr);
  k_conv<<<dim3(16, 81), 1024, 0, stream>>>(braw0, nullptr, Wmf, P,
                                            1, braw1, nullptr);
  k_conv<<<dim3(16, 81), 1024, 0, stream>>>(braw1, braw0, Wmf, P,
                                            2, nullptr, xrb);
  // fused inverse angular DCT (preload-81 registers, in-kernel Da)
  k_anginv<<<576, 256, 0, stream>>>(xrb, R1);
  // fused inverse spatial DCT + residual add (in-LDS inverse table)
  k_dct2<<<243, 1024, 135168, stream>>>(R1, x, (float*)d_out, nullptr, P, Wmf);
}